// Round 1
// baseline (578.343 us; speedup 1.0000x reference)
//
#include <hip/hip_runtime.h>
#include <hip/hip_bf16.h>

// Problem constants
#define BB 4
#define TT 2048
#define CCH 1024
#define NHH 16
#define HSS 64
// derived
#define MROWS (BB * TT)          // 8192
#define QKV_ELEMS (64 * 2048 * 64) // per-tensor elems in [B*NH][T][HS] = 8388608

typedef __attribute__((ext_vector_type(8))) short short8;
typedef __attribute__((ext_vector_type(4))) float f32x4;

static __device__ __forceinline__ unsigned short bf16_of(float f) {
  union { float f; unsigned u; } v; v.f = f;
  unsigned u = v.u;
  return (unsigned short)((u + 0x7FFFu + ((u >> 16) & 1u)) >> 16);
}

// ---------------- cast kernels ----------------
__global__ __launch_bounds__(256) void cast_f32_bf16(const float* __restrict__ in,
                                                     unsigned short* __restrict__ out, int n) {
  int i = (blockIdx.x * 256 + threadIdx.x) * 4;
  if (i < n) {
    float4 f = *reinterpret_cast<const float4*>(in + i);
    ushort4 o;
    o.x = bf16_of(f.x); o.y = bf16_of(f.y); o.z = bf16_of(f.z); o.w = bf16_of(f.w);
    *reinterpret_cast<ushort4*>(out + i) = o;
  }
}

// in: [K][N] f32 row-major  ->  out: [N][K] bf16 row-major
__global__ __launch_bounds__(256) void transpose_cast(const float* __restrict__ in,
                                                      unsigned short* __restrict__ out,
                                                      int K, int N) {
  int idx = blockIdx.x * 256 + threadIdx.x;
  if (idx < K * N) {
    int k = idx / N;
    int n = idx - k * N;
    out[(size_t)n * K + k] = bf16_of(in[idx]);
  }
}

// ---------------- GEMM: C = A[M,K] @ Bt[N,K]^T + bias ----------------
// MODE 0: write fp32 out[M,N]
// MODE 1: scatter QKV epilogue -> bf16 q/k/v in [B*NH][T][HS] layout
template <int MODE>
__global__ __launch_bounds__(256) void gemm_bt(const unsigned short* __restrict__ A,
                                               const unsigned short* __restrict__ Bt,
                                               const float* __restrict__ bias,
                                               float* __restrict__ outF,
                                               unsigned short* __restrict__ outQKV,
                                               int M, int N, int K) {
  __shared__ unsigned short As[128][40];
  __shared__ unsigned short Bs[128][40];
  int tid = threadIdx.x;
  int w = tid >> 6, lane = tid & 63;
  int g = lane >> 4, r16 = lane & 15;
  int wr = w >> 1, wc = w & 1;
  int m0 = blockIdx.y * 128, n0 = blockIdx.x * 128;

  f32x4 zero = {0.f, 0.f, 0.f, 0.f};
  f32x4 acc[4][4];
#pragma unroll
  for (int i = 0; i < 4; ++i)
#pragma unroll
    for (int n = 0; n < 4; ++n) acc[i][n] = zero;

  for (int kt = 0; kt < K; kt += 32) {
#pragma unroll
    for (int it = 0; it < 2; ++it) {
      int flat = tid + it * 256;
      int row = flat >> 2, kc = (flat & 3) * 8;
      *reinterpret_cast<int4*>(&As[row][kc]) =
          *reinterpret_cast<const int4*>(&A[(size_t)(m0 + row) * K + kt + kc]);
      *reinterpret_cast<int4*>(&Bs[row][kc]) =
          *reinterpret_cast<const int4*>(&Bt[(size_t)(n0 + row) * K + kt + kc]);
    }
    __syncthreads();
    short8 af[4], bfr[4];
#pragma unroll
    for (int i = 0; i < 4; ++i)
      af[i] = *reinterpret_cast<const short8*>(&As[wr * 64 + i * 16 + r16][g * 8]);
#pragma unroll
    for (int i = 0; i < 4; ++i)
      bfr[i] = *reinterpret_cast<const short8*>(&Bs[wc * 64 + i * 16 + r16][g * 8]);
#pragma unroll
    for (int i = 0; i < 4; ++i)
#pragma unroll
      for (int n = 0; n < 4; ++n)
        acc[i][n] = __builtin_amdgcn_mfma_f32_16x16x32_bf16(af[i], bfr[n], acc[i][n], 0, 0, 0);
    __syncthreads();
  }

#pragma unroll
  for (int i = 0; i < 4; ++i)
#pragma unroll
    for (int n = 0; n < 4; ++n)
#pragma unroll
      for (int j = 0; j < 4; ++j) {
        int row = m0 + wr * 64 + i * 16 + g * 4 + j;
        int col = n0 + wc * 64 + n * 16 + r16;
        float val = acc[i][n][j] + bias[col];
        if (MODE == 0) {
          outF[(size_t)row * N + col] = val;
        } else {
          int which = col >> 10, c = col & 1023;
          int h = c >> 6, d = c & 63;
          int b = row >> 11, t = row & 2047;
          outQKV[(size_t)which * QKV_ELEMS +
                 (((size_t)(b * 16 + h) * 2048 + t) * 64 + d)] = bf16_of(val);
        }
      }
}

// ---------------- causal flash attention ----------------
// Q,K,V: [B*NH][T][HS] bf16.  Y: [B][T][C] bf16.
__global__ __launch_bounds__(256) void attn_kernel(const unsigned short* __restrict__ Qm,
                                                   const unsigned short* __restrict__ Km,
                                                   const unsigned short* __restrict__ Vm,
                                                   unsigned short* __restrict__ Y) {
  __shared__ unsigned short Vt[64][40];   // V^T tile: [d][key]
  __shared__ unsigned short P[4][16][32]; // per-wave P tile

  int tid = threadIdx.x;
  int w = tid >> 6, lane = tid & 63;
  int g = lane >> 4, r16 = lane & 15;
  int bh = blockIdx.y;        // 0..63
  int q0 = blockIdx.x * 64;
  int qw0 = q0 + w * 16;
  const size_t base = (size_t)bh * TT * HSS;

  short8 qf[2];
#pragma unroll
  for (int c = 0; c < 2; ++c)
    qf[c] = *reinterpret_cast<const short8*>(&Qm[base + (size_t)(qw0 + r16) * 64 + c * 32 + g * 8]);

  f32x4 zero = {0.f, 0.f, 0.f, 0.f};
  f32x4 o[4];
#pragma unroll
  for (int ng = 0; ng < 4; ++ng) o[ng] = zero;
  float mrow[4], lrow[4];
#pragma unroll
  for (int j = 0; j < 4; ++j) { mrow[j] = -1e30f; lrow[j] = 0.f; }

  int nt = (q0 + 64) >> 5;
  for (int kt = 0; kt < nt; ++kt) {
    int key0 = kt << 5;
    __syncthreads(); // protect Vt/P from previous iteration's reads
    { // stage V^T tile
      int kk = tid >> 3, dc = (tid & 7) * 8;
      short8 vv = *reinterpret_cast<const short8*>(&Vm[base + (size_t)(key0 + kk) * 64 + dc]);
#pragma unroll
      for (int i = 0; i < 8; ++i) Vt[dc + i][kk] = (unsigned short)vv[i];
    }
    __syncthreads();
    bool active = (key0 <= qw0 + 15);
    float p0[4], p1[4];
    if (active) {
      short8 kf0[2], kf1[2];
#pragma unroll
      for (int c = 0; c < 2; ++c) {
        kf0[c] = *reinterpret_cast<const short8*>(&Km[base + (size_t)(key0 + r16) * 64 + c * 32 + g * 8]);
        kf1[c] = *reinterpret_cast<const short8*>(&Km[base + (size_t)(key0 + 16 + r16) * 64 + c * 32 + g * 8]);
      }
      f32x4 s0 = zero, s1 = zero;
      s0 = __builtin_amdgcn_mfma_f32_16x16x32_bf16(qf[0], kf0[0], s0, 0, 0, 0);
      s0 = __builtin_amdgcn_mfma_f32_16x16x32_bf16(qf[1], kf0[1], s0, 0, 0, 0);
      s1 = __builtin_amdgcn_mfma_f32_16x16x32_bf16(qf[0], kf1[0], s1, 0, 0, 0);
      s1 = __builtin_amdgcn_mfma_f32_16x16x32_bf16(qf[1], kf1[1], s1, 0, 0, 0);

      float al[4];
#pragma unroll
      for (int j = 0; j < 4; ++j) {
        int row = qw0 + g * 4 + j;
        float v0 = s0[j] * 0.125f;
        if (key0 + r16 > row) v0 = -1e30f;
        float v1 = s1[j] * 0.125f;
        if (key0 + 16 + r16 > row) v1 = -1e30f;
        float vm = fmaxf(v0, v1);
#pragma unroll
        for (int off = 1; off < 16; off <<= 1) vm = fmaxf(vm, __shfl_xor(vm, off));
        float mn = fmaxf(mrow[j], vm);
        float a = __expf(mrow[j] - mn);
        p0[j] = __expf(v0 - mn);
        p1[j] = __expf(v1 - mn);
        float rs = p0[j] + p1[j];
#pragma unroll
        for (int off = 1; off < 16; off <<= 1) rs += __shfl_xor(rs, off);
        lrow[j] = lrow[j] * a + rs;
        mrow[j] = mn;
        al[j] = a;
      }
#pragma unroll
      for (int ng = 0; ng < 4; ++ng)
#pragma unroll
        for (int j = 0; j < 4; ++j) o[ng][j] *= al[j];
      // write P tile (C-layout -> LDS)
#pragma unroll
      for (int j = 0; j < 4; ++j) {
        P[w][g * 4 + j][r16] = bf16_of(p0[j]);
        P[w][g * 4 + j][16 + r16] = bf16_of(p1[j]);
      }
    }
    __syncthreads(); // make P visible (uniform across waves)
    if (active) {
      short8 pf = *reinterpret_cast<const short8*>(&P[w][r16][g * 8]);
#pragma unroll
      for (int ng = 0; ng < 4; ++ng) {
        short8 vf = *reinterpret_cast<const short8*>(&Vt[ng * 16 + r16][g * 8]);
        o[ng] = __builtin_amdgcn_mfma_f32_16x16x32_bf16(pf, vf, o[ng], 0, 0, 0);
      }
    }
  }

  int b = bh >> 4, h = bh & 15;
#pragma unroll
  for (int ng = 0; ng < 4; ++ng)
#pragma unroll
    for (int j = 0; j < 4; ++j) {
      int t = qw0 + g * 4 + j;
      float val = o[ng][j] / lrow[j];
      Y[((size_t)(b * TT + t) * CCH) + h * 64 + ng * 16 + r16] = bf16_of(val);
    }
}

// ---------------- host ----------------
extern "C" void kernel_launch(void* const* d_in, const int* in_sizes, int n_in,
                              void* d_out, int out_size, void* d_ws, size_t ws_size,
                              hipStream_t stream) {
  const float* x      = (const float*)d_in[0];
  const float* w_attn = (const float*)d_in[1];
  const float* b_attn = (const float*)d_in[2];
  const float* w_proj = (const float*)d_in[3];
  const float* b_proj = (const float*)d_in[4];
  float* out = (float*)d_out;

  char* ws = (char*)d_ws;
  unsigned short* xb  = (unsigned short*)(ws + 0);          // 8192x1024 bf16 (16.78 MB) ; reused as Y
  unsigned short* wta = (unsigned short*)(ws + 16777216);   // 3072x1024 bf16
  unsigned short* wtp = (unsigned short*)(ws + 23068672);   // 1024x1024 bf16
  unsigned short* qb  = (unsigned short*)(ws + 25165824);   // [64][2048][64] bf16
  unsigned short* yb  = xb;                                  // reuse (x dead after QKV GEMM)

  // 1) casts
  cast_f32_bf16<<<(MROWS * CCH) / 1024, 256, 0, stream>>>(x, xb, MROWS * CCH);
  transpose_cast<<<(CCH * 3 * CCH + 255) / 256, 256, 0, stream>>>(w_attn, wta, CCH, 3 * CCH);
  transpose_cast<<<(CCH * CCH + 255) / 256, 256, 0, stream>>>(w_proj, wtp, CCH, CCH);

  // 2) QKV GEMM: [8192,1024] @ [1024,3072] -> scatter q/k/v
  {
    dim3 grid(3 * CCH / 128, MROWS / 128);
    gemm_bt<1><<<grid, 256, 0, stream>>>(xb, wta, b_attn, nullptr, qb, MROWS, 3 * CCH, CCH);
  }

  // 3) attention -> Y [B,T,C] bf16 (into xb region)
  {
    dim3 grid(TT / 64, BB * NHH);
    attn_kernel<<<grid, 256, 0, stream>>>(qb, qb + (size_t)QKV_ELEMS, qb + 2 * (size_t)QKV_ELEMS, yb);
  }

  // 4) projection GEMM: [8192,1024] @ [1024,1024] + bias -> fp32 out
  {
    dim3 grid(CCH / 128, MROWS / 128);
    gemm_bt<0><<<grid, 256, 0, stream>>>(yb, wtp, b_proj, out, nullptr, MROWS, CCH, CCH);
  }
}